// Round 9
// baseline (367.861 us; speedup 1.0000x reference)
//
#include <hip/hip_runtime.h>
#include <math.h>

#define MAXB 512
#define PART_BS 1024
#define NBLK_MAX 248
#define CAPB 96  // per-(block,bucket) segment capacity; %8==0

typedef _Float16 f16;
typedef __attribute__((ext_vector_type(2))) _Float16 f16x2;
typedef __attribute__((ext_vector_type(4))) _Float16 f16x4;
typedef __attribute__((ext_vector_type(8))) _Float16 f16x8;
typedef __attribute__((ext_vector_type(4))) float f32x4;

static __device__ __forceinline__ unsigned short f2h(float f) {
    f16 h = (f16)f; return *(unsigned short*)&h;
}

// ========== single-pass partition into per-block private segments ==========
// bb[(bucket*nblk + blk)*CAPB + r]; block 0 additionally converts weights.
__global__ __launch_bounds__(PART_BS) void k_part(
    const int* __restrict__ src, const int* __restrict__ dst,
    unsigned* __restrict__ bb, int* __restrict__ cnt,
    const float* __restrict__ lin1_w, const float* __restrict__ c1_wl,
    const float* __restrict__ c1_wr, const float* __restrict__ lin2_w,
    const float* __restrict__ c2_wl, const float* __restrict__ c2_wr,
    const float* __restrict__ mlp_w1, const float* __restrict__ mlp_w2,
    unsigned short* __restrict__ Wt,
    int E, int shift, int pcap, int nblk, int nb) {
    __shared__ int h[MAXB];
    const int blk = blockIdx.x;
    if (blk == 0) {  // fused weight prep
        for (int i = threadIdx.x; i < 36928; i += PART_BS) {
            float v;
            if (i < 8192)       { int j = i;         int n = j >> 7, k = j & 127; v = lin1_w[k * 64 + n]; }
            else if (i < 16384) { int j = i - 8192;  int n = j >> 7, k = j & 127;
                                  v = (k < 64) ? c1_wl[k * 64 + n] : c1_wr[(k - 64) * 64 + n]; }
            else if (i < 20480) { int j = i - 16384; int n = j >> 6, k = j & 63;  v = lin2_w[k * 64 + n]; }
            else if (i < 28672) { int j = i - 20480; int n = j >> 7, k = j & 127;
                                  v = (k < 64) ? c2_wl[k * 64 + n] : c2_wr[(k - 64) * 64 + n]; }
            else if (i < 32768) { int j = i - 28672; int n = j >> 6, k = j & 63;  v = mlp_w1[k * 64 + n]; }
            else if (i < 36864) { int j = i - 32768; int n = j >> 6, k = j & 63;  v = mlp_w1[(k + 64) * 64 + n]; }
            else                { v = mlp_w2[i - 36864]; }
            Wt[i] = f2h(v);
        }
    }
    const int b0 = blk * pcap;
    const int e1 = min(b0 + pcap, E);
    for (int i = threadIdx.x; i < MAXB; i += PART_BS) h[i] = 0;
    __syncthreads();
    const unsigned mask = (1u << shift) - 1u;
    for (int pos = b0 + (int)threadIdx.x * 8; pos < e1; pos += PART_BS * 8) {
        if (pos + 8 <= e1) {
            int4 d0 = *(const int4*)(dst + pos), d1 = *(const int4*)(dst + pos + 4);
            int4 s0 = *(const int4*)(src + pos), s1 = *(const int4*)(src + pos + 4);
            int dd[8] = {d0.x, d0.y, d0.z, d0.w, d1.x, d1.y, d1.z, d1.w};
            int ss[8] = {s0.x, s0.y, s0.z, s0.w, s1.x, s1.y, s1.z, s1.w};
#pragma unroll
            for (int k = 0; k < 8; ++k) {
                int b = dd[k] >> shift;
                int r = atomicAdd(&h[b], 1);
                if (r < CAPB)
                    bb[((size_t)b * nblk + blk) * CAPB + r] =
                        ((unsigned)ss[k] << shift) | ((unsigned)dd[k] & mask);
            }
        } else {
            for (int k = 0; pos + k < e1; ++k) {
                int d = dst[pos + k];
                int b = d >> shift;
                int r = atomicAdd(&h[b], 1);
                if (r < CAPB)
                    bb[((size_t)b * nblk + blk) * CAPB + r] =
                        ((unsigned)src[pos + k] << shift) | ((unsigned)d & mask);
            }
        }
    }
    __syncthreads();
    for (int i = threadIdx.x; i < nb; i += PART_BS)
        cnt[(size_t)i * nblk + blk] = min(h[i], CAPB);
}

// ========== FUSED: bfill (CSR build) + mm1 (h1 = relu(x@lin1_w+b)) ==========
// blockIdx < nbB: bfill role; else mm1 role. SAFE: bb aliases aggH/Qh (not
// Hh), so mm1's Hh writes never touch memory bfill still reads. Both roles
// depend only on k_part's outputs; outputs disjoint.
__global__ __launch_bounds__(512) void k_bfmm(
    const unsigned* __restrict__ bb, const int* __restrict__ cnt,
    int* __restrict__ row_st, int* __restrict__ row_en,
    float* __restrict__ inv_deg, int* __restrict__ csr,
    int N, int shift, int CAP, int nblk, int nbB,
    const float* __restrict__ x, const unsigned short* __restrict__ Wtg,
    const float* __restrict__ bias, unsigned short* __restrict__ outh) {
    __shared__ alignas(16) unsigned char smem[64 * 136 * 2];  // 17408 B union
    const int t = threadIdx.x;

    if (blockIdx.x < (unsigned)nbB) {
        // ---------------- bfill role (8-wide slot batching) ----------------
        int* deg  = (int*)smem;            // 512
        int* cur  = deg + 512;             // 512
        int* s    = cur + 512;             // 512
        int* scnt = s + 512;               // NBLK_MAX
        int b = blockIdx.x;
        int lo = b << shift;
        int hi = min(N, (b + 1) << shift);
        int nn = hi - lo;
        unsigned off = (unsigned)b * CAP;
        unsigned mask = (1u << shift) - 1u;
        const unsigned* seg = bb + (size_t)b * nblk * CAPB;

        for (int i = t; i < nblk; i += 512) scnt[i] = cnt[(size_t)b * nblk + i];
        deg[t] = 0;
        __syncthreads();
        const int tot8 = (nblk * CAPB) >> 3;
        for (int q8 = t; q8 < tot8; q8 += 512) {
            int i = q8 << 3;
            int si = i / CAPB;             // compile-time-const divisor
            int r = i - si * CAPB;
            int sc = scnt[si];
            if (r < sc) {
                uint4 wA = *(const uint4*)&seg[i];
                uint4 wB = *(const uint4*)&seg[i + 4];
                int nv = min(sc - r, 8);
                unsigned ww[8] = {wA.x, wA.y, wA.z, wA.w, wB.x, wB.y, wB.z, wB.w};
#pragma unroll
                for (int k = 0; k < 8; ++k)
                    if (k < nv) atomicAdd(&deg[ww[k] & mask], 1);
            }
        }
        __syncthreads();
        int d = deg[t];
        int pd = (d + 31) & ~31;
        s[t] = pd;
        __syncthreads();
        for (int o = 1; o < 512; o <<= 1) {
            int u = (t >= o) ? s[t - o] : 0;
            __syncthreads();
            s[t] += u;
            __syncthreads();
        }
        int excl = min(s[t] - pd, CAP);
        int pe = min(excl + pd, CAP);
        cur[t] = excl;
        if (t < nn) {
            row_st[lo + t] = (int)off + excl;
            row_en[lo + t] = (int)off + pe;
            inv_deg[lo + t] = d > 0 ? 1.0f / (float)d : 0.0f;
            for (int j = excl + d; j < pe; ++j) csr[off + j] = N;  // sentinel
        }
        __syncthreads();
        for (int q8 = t; q8 < tot8; q8 += 512) {
            int i = q8 << 3;
            int si = i / CAPB;
            int r = i - si * CAPB;
            int sc = scnt[si];
            if (r < sc) {
                uint4 wA = *(const uint4*)&seg[i];
                uint4 wB = *(const uint4*)&seg[i + 4];
                int nv = min(sc - r, 8);
                unsigned ww[8] = {wA.x, wA.y, wA.z, wA.w, wB.x, wB.y, wB.z, wB.w};
#pragma unroll
                for (int k = 0; k < 8; ++k)
                    if (k < nv) {
                        int dl = (int)(ww[k] & mask);
                        int pos = atomicAdd(&cur[dl], 1);
                        if (pos < CAP) csr[off + pos] = (int)(ww[k] >> shift);
                    }
            }
        }
    } else {
        // ---------------- mm1 role: 128 rows/block, 8 waves ----------------
        unsigned short* sW = (unsigned short*)smem;   // 64*136 halfs
        const int mb = blockIdx.x - nbB;
        const int row0 = mb * 128;
        const int n = N;
        if (mb == 0 && t < 8)
            ((uint4*)(outh + (size_t)n * 64))[t] = (uint4){0, 0, 0, 0};  // sentinel row
        for (int i = t; i < 64 * 16; i += 512) {
            int nn = i >> 4, c = i & 15;
            *(uint4*)&sW[(nn * 17 + c) * 8] = *(const uint4*)&Wtg[i * 8];
        }
        __syncthreads();
        const int lane = t & 63, w = t >> 6;      // w in 0..7
        const int m = lane & 15, q = lane >> 4;
        const int gr = min(row0 + 16 * w + m, n - 1);
        const float* ar = x + (size_t)gr * 128;
        f32x4 acc[4];
#pragma unroll
        for (int c = 0; c < 4; ++c) acc[c] = (f32x4){0.f, 0.f, 0.f, 0.f};
#pragma unroll
        for (int kk = 0; kk < 4; ++kk) {
            float4 a0 = *(const float4*)(ar + kk * 32 + q * 8);
            float4 a1 = *(const float4*)(ar + kk * 32 + q * 8 + 4);
            f16x8 af;
            af[0] = (f16)a0.x; af[1] = (f16)a0.y; af[2] = (f16)a0.z; af[3] = (f16)a0.w;
            af[4] = (f16)a1.x; af[5] = (f16)a1.y; af[6] = (f16)a1.z; af[7] = (f16)a1.w;
#pragma unroll
            for (int c = 0; c < 4; ++c) {
                f16x8 bf = *(const f16x8*)&sW[((16 * c + m) * 17 + (kk * 4 + q)) * 8];
                acc[c] = __builtin_amdgcn_mfma_f32_16x16x32_f16(af, bf, acc[c], 0, 0, 0);
            }
        }
#pragma unroll
        for (int c = 0; c < 4; ++c) {
            int col = 16 * c + m;
            float bv = bias[col];
#pragma unroll
            for (int i = 0; i < 4; ++i) {
                int r = row0 + 16 * w + q * 4 + i;
                if (r < n) outh[(size_t)r * 64 + col] = f2h(fmaxf(acc[c][i] + bv, 0.f));
            }
        }
    }
}

// ====== mean aggregation v6: sentinel-padded rows, 64-row chunks ======
// lane: g = lane>>3 (row slot 0..7), sub = lane&7 (channel octet)
__global__ __launch_bounds__(256) void k_gather_h(
    const _Float16* __restrict__ hh, const int* __restrict__ csr,
    const int* __restrict__ row_st, const int* __restrict__ row_en,
    const float* __restrict__ inv_deg, _Float16* __restrict__ out, int n) {
    int node = (blockIdx.x * 256 + (int)threadIdx.x) >> 6;
    if (node >= n) return;
    int lane = threadIdx.x & 63;
    int g = lane >> 3, sub = lane & 7;
    int base = row_st[node], end = row_en[node];
    float a[8] = {0.f, 0.f, 0.f, 0.f, 0.f, 0.f, 0.f, 0.f};
#if __has_builtin(__builtin_amdgcn_fdot2)
    const f16x2 one2 = {(f16)1.f, (f16)1.f};
#endif
    for (; base + 64 <= end; base += 64) {
        int4 sA = *(const int4*)&csr[base + 4 * g];
        int4 sB = *(const int4*)&csr[base + 32 + 4 * g];
        int sidx[8] = {sA.x, sA.y, sA.z, sA.w, sB.x, sB.y, sB.z, sB.w};
        f16x8 u[8];
#pragma unroll
        for (int t = 0; t < 8; ++t)
            u[t] = *(const f16x8*)(hh + (((unsigned)sidx[t] << 6) + ((unsigned)sub << 3)));
#if __has_builtin(__builtin_amdgcn_fdot2)
#pragma unroll
        for (int t = 0; t < 8; t += 2)
#pragma unroll
            for (int j = 0; j < 8; ++j) {
                f16x2 v = {u[t][j], u[t + 1][j]};
                a[j] = __builtin_amdgcn_fdot2(v, one2, a[j], false);
            }
#else
#pragma unroll
        for (int t = 0; t < 8; ++t)
#pragma unroll
            for (int j = 0; j < 8; ++j) a[j] += (float)u[t][j];
#endif
    }
    if (base < end) {  // one 32-row tail (rows padded to x32)
        int4 sA = *(const int4*)&csr[base + 4 * g];
        int sidx[4] = {sA.x, sA.y, sA.z, sA.w};
        f16x8 u[4];
#pragma unroll
        for (int t = 0; t < 4; ++t)
            u[t] = *(const f16x8*)(hh + (((unsigned)sidx[t] << 6) + ((unsigned)sub << 3)));
#if __has_builtin(__builtin_amdgcn_fdot2)
#pragma unroll
        for (int t = 0; t < 4; t += 2)
#pragma unroll
            for (int j = 0; j < 8; ++j) {
                f16x2 v = {u[t][j], u[t + 1][j]};
                a[j] = __builtin_amdgcn_fdot2(v, one2, a[j], false);
            }
#else
#pragma unroll
        for (int t = 0; t < 4; ++t)
#pragma unroll
            for (int j = 0; j < 8; ++j) a[j] += (float)u[t][j];
#endif
    }
#pragma unroll
    for (int j = 0; j < 8; ++j) {
        a[j] += __shfl_xor(a[j], 8, 64);
        a[j] += __shfl_xor(a[j], 16, 64);
        a[j] += __shfl_xor(a[j], 32, 64);
    }
    if (g == 0) {
        float idv = inv_deg[node];
        f16x8 o;
#pragma unroll
        for (int j = 0; j < 8; ++j) o[j] = (f16)(a[j] * idv);
        *(f16x8*)(out + (((unsigned)node << 6) + ((unsigned)sub << 3))) = o;
    }
}

// ---- k_mm23 (MFMA, 2-stage): h3 = relu(relu([agg|h1]@Wc+bl) @ lin2 + b2) ----
__global__ __launch_bounds__(256) void k_mm23(
    const unsigned short* __restrict__ aggH, const unsigned short* __restrict__ h1,
    const unsigned short* __restrict__ Wcg, const float* __restrict__ bl,
    const unsigned short* __restrict__ Wl2g, const float* __restrict__ b2,
    unsigned short* __restrict__ outh, int n) {
    __shared__ alignas(16) unsigned short sm[64 * 72 + 64 * 136];
    unsigned short* hA = sm;
    unsigned short* sW = sm + 64 * 72;
    const int tid = threadIdx.x;
    const int row0 = blockIdx.x * 64;
    for (int i = tid; i < 64 * 16; i += 256) {
        int nn = i >> 4, c = i & 15;
        *(uint4*)&sW[(nn * 17 + c) * 8] = *(const uint4*)&Wcg[i * 8];
    }
    __syncthreads();
    const int lane = tid & 63, w = tid >> 6;
    const int m = lane & 15, q = lane >> 4;
    const int gr = min(row0 + 16 * w + m, n - 1);
    f32x4 acc[4];
#pragma unroll
    for (int c = 0; c < 4; ++c) acc[c] = (f32x4){0.f, 0.f, 0.f, 0.f};
#pragma unroll
    for (int kk = 0; kk < 4; ++kk) {
        const unsigned short* ap = (kk < 2)
            ? (aggH + (size_t)gr * 64 + kk * 32 + q * 8)
            : (h1 + (size_t)gr * 64 + (kk - 2) * 32 + q * 8);
        f16x8 af = *(const f16x8*)ap;
#pragma unroll
        for (int c = 0; c < 4; ++c) {
            f16x8 bf = *(const f16x8*)&sW[((16 * c + m) * 17 + (kk * 4 + q)) * 8];
            acc[c] = __builtin_amdgcn_mfma_f32_16x16x32_f16(af, bf, acc[c], 0, 0, 0);
        }
    }
#pragma unroll
    for (int c = 0; c < 4; ++c) {
        int col = 16 * c + m;
        float bv = bl[col];
#pragma unroll
        for (int i = 0; i < 4; ++i)
            hA[(16 * w + q * 4 + i) * 72 + col] = f2h(fmaxf(acc[c][i] + bv, 0.f));
    }
    __syncthreads();
    for (int i = tid; i < 64 * 8; i += 256) {
        int nn = i >> 3, c = i & 7;
        *(uint4*)&sW[(nn * 9 + c) * 8] = *(const uint4*)&Wl2g[i * 8];
    }
    __syncthreads();
    f32x4 acc2[4];
#pragma unroll
    for (int c = 0; c < 4; ++c) acc2[c] = (f32x4){0.f, 0.f, 0.f, 0.f};
#pragma unroll
    for (int kk = 0; kk < 2; ++kk) {
        f16x8 af = *(const f16x8*)&hA[(16 * w + m) * 72 + kk * 32 + q * 8];
#pragma unroll
        for (int c = 0; c < 4; ++c) {
            f16x8 bf = *(const f16x8*)&sW[((16 * c + m) * 9 + (kk * 4 + q)) * 8];
            acc2[c] = __builtin_amdgcn_mfma_f32_16x16x32_f16(af, bf, acc2[c], 0, 0, 0);
        }
    }
#pragma unroll
    for (int c = 0; c < 4; ++c) {
        int col = 16 * c + m;
        float bv = b2[col];
#pragma unroll
        for (int i = 0; i < 4; ++i) {
            int r = row0 + 16 * w + q * 4 + i;
            if (r < n) outh[(size_t)r * 64 + col] = f2h(fmaxf(acc2[c][i] + bv, 0.f));
        }
    }
}

// ---- k_mm456 (MFMA, 2-stage): h4=relu([agg2|h3]@Wc2+bl); P=h4@Wp+b1; Q=h4@Wq
__global__ __launch_bounds__(256) void k_mm456(
    const unsigned short* __restrict__ aggH, const unsigned short* __restrict__ h3,
    const unsigned short* __restrict__ Wcg, const float* __restrict__ bl,
    const unsigned short* __restrict__ Wpg, const unsigned short* __restrict__ Wqg,
    const float* __restrict__ b1, unsigned short* __restrict__ Ph,
    unsigned short* __restrict__ Qh, int n) {
    __shared__ alignas(16) unsigned short sm[64 * 72 + 2 * 64 * 72];
    unsigned short* hA = sm;
    unsigned short* sW = sm + 64 * 72;
    const int tid = threadIdx.x;
    const int row0 = blockIdx.x * 64;
    for (int i = tid; i < 64 * 16; i += 256) {
        int nn = i >> 4, c = i & 15;
        *(uint4*)&sW[(nn * 17 + c) * 8] = *(const uint4*)&Wcg[i * 8];
    }
    __syncthreads();
    const int lane = tid & 63, w = tid >> 6;
    const int m = lane & 15, q = lane >> 4;
    const int gr = min(row0 + 16 * w + m, n - 1);
    f32x4 acc[4];
#pragma unroll
    for (int c = 0; c < 4; ++c) acc[c] = (f32x4){0.f, 0.f, 0.f, 0.f};
#pragma unroll
    for (int kk = 0; kk < 4; ++kk) {
        const unsigned short* ap = (kk < 2)
            ? (aggH + (size_t)gr * 64 + kk * 32 + q * 8)
            : (h3 + (size_t)gr * 64 + (kk - 2) * 32 + q * 8);
        f16x8 af = *(const f16x8*)ap;
#pragma unroll
        for (int c = 0; c < 4; ++c) {
            f16x8 bf = *(const f16x8*)&sW[((16 * c + m) * 17 + (kk * 4 + q)) * 8];
            acc[c] = __builtin_amdgcn_mfma_f32_16x16x32_f16(af, bf, acc[c], 0, 0, 0);
        }
    }
#pragma unroll
    for (int c = 0; c < 4; ++c) {
        int col = 16 * c + m;
        float bv = bl[col];
#pragma unroll
        for (int i = 0; i < 4; ++i)
            hA[(16 * w + q * 4 + i) * 72 + col] = f2h(fmaxf(acc[c][i] + bv, 0.f));
    }
    __syncthreads();
    for (int i = tid; i < 64 * 8; i += 256) {
        int nn = i >> 3, c = i & 7;
        *(uint4*)&sW[(nn * 9 + c) * 8] = *(const uint4*)&Wpg[i * 8];
        *(uint4*)&sW[4608 + (nn * 9 + c) * 8] = *(const uint4*)&Wqg[i * 8];
    }
    __syncthreads();
    f32x4 accP[4], accQ[4];
#pragma unroll
    for (int c = 0; c < 4; ++c) {
        accP[c] = (f32x4){0.f, 0.f, 0.f, 0.f};
        accQ[c] = (f32x4){0.f, 0.f, 0.f, 0.f};
    }
#pragma unroll
    for (int kk = 0; kk < 2; ++kk) {
        f16x8 af = *(const f16x8*)&hA[(16 * w + m) * 72 + kk * 32 + q * 8];
#pragma unroll
        for (int c = 0; c < 4; ++c) {
            f16x8 bp = *(const f16x8*)&sW[((16 * c + m) * 9 + (kk * 4 + q)) * 8];
            f16x8 bq = *(const f16x8*)&sW[4608 + ((16 * c + m) * 9 + (kk * 4 + q)) * 8];
            accP[c] = __builtin_amdgcn_mfma_f32_16x16x32_f16(af, bp, accP[c], 0, 0, 0);
            accQ[c] = __builtin_amdgcn_mfma_f32_16x16x32_f16(af, bq, accQ[c], 0, 0, 0);
        }
    }
#pragma unroll
    for (int c = 0; c < 4; ++c) {
        int col = 16 * c + m;
        float bv = b1[col];
#pragma unroll
        for (int i = 0; i < 4; ++i) {
            int r = row0 + 16 * w + q * 4 + i;
            if (r < n) {
                Ph[(size_t)r * 64 + col] = f2h(accP[c][i] + bv);
                Qh[(size_t)r * 64 + col] = f2h(accQ[c][i]);
            }
        }
    }
}

// ---- edge scorer v3: 8 lanes/edge, f16x8, 16 loads in flight per wave ----
__global__ __launch_bounds__(256) void k_score_h(
    const _Float16* __restrict__ P, const _Float16* __restrict__ Q,
    const int* __restrict__ msrc, const int* __restrict__ mdst,
    const _Float16* __restrict__ w2h, const float* __restrict__ b2,
    float* __restrict__ out, int M) {
    int gid = blockIdx.x * 256 + threadIdx.x;
    int e = gid >> 3;
    if (e >= M) return;
    int l = gid & 7;
    int s = msrc[e], d = mdst[e];
    f16x8 p = *(const f16x8*)(P + (((unsigned)s << 6) + ((unsigned)l << 3)));
    f16x8 q = *(const f16x8*)(Q + (((unsigned)d << 6) + ((unsigned)l << 3)));
    f16x8 w = *(const f16x8*)(w2h + ((unsigned)l << 3));
    f16x8 u = p + q;
    f16x8 z = {(f16)0, (f16)0, (f16)0, (f16)0, (f16)0, (f16)0, (f16)0, (f16)0};
    u = __builtin_elementwise_max(u, z);
    float partial;
#if __has_builtin(__builtin_amdgcn_fdot2)
    f16x2 u01 = {u[0], u[1]}, u23 = {u[2], u[3]}, u45 = {u[4], u[5]}, u67 = {u[6], u[7]};
    f16x2 w01 = {w[0], w[1]}, w23 = {w[2], w[3]}, w45 = {w[4], w[5]}, w67 = {w[6], w[7]};
    partial = __builtin_amdgcn_fdot2(u01, w01,
              __builtin_amdgcn_fdot2(u23, w23,
              __builtin_amdgcn_fdot2(u45, w45,
              __builtin_amdgcn_fdot2(u67, w67, 0.f, false), false), false), false);
#else
    partial = 0.f;
#pragma unroll
    for (int i = 0; i < 8; ++i) partial += (float)u[i] * (float)w[i];
#endif
    partial += __shfl_xor(partial, 1, 8);
    partial += __shfl_xor(partial, 2, 8);
    partial += __shfl_xor(partial, 4, 8);
    if (l == 0) {
        float xx = partial + b2[0];
        float t = __expf(2.f * xx);
        out[e] = (t - 1.f) / (t + 1.f);
    }
}

extern "C" void kernel_launch(void* const* d_in, const int* in_sizes, int n_in,
                              void* d_out, int out_size, void* d_ws, size_t ws_size,
                              hipStream_t stream) {
    const float* x      = (const float*)d_in[0];
    const int*   ei     = (const int*)d_in[1];
    const int*   mei    = (const int*)d_in[2];
    const float* lin1_w = (const float*)d_in[3];
    const float* lin1_b = (const float*)d_in[4];
    const float* lin2_w = (const float*)d_in[5];
    const float* lin2_b = (const float*)d_in[6];
    const float* c1_wl  = (const float*)d_in[7];
    const float* c1_bl  = (const float*)d_in[8];
    const float* c1_wr  = (const float*)d_in[9];
    const float* c2_wl  = (const float*)d_in[10];
    const float* c2_bl  = (const float*)d_in[11];
    const float* c2_wr  = (const float*)d_in[12];
    const float* mlp_w1 = (const float*)d_in[13];
    const float* mlp_b1 = (const float*)d_in[14];
    const float* mlp_w2 = (const float*)d_in[15];
    const float* mlp_b2 = (const float*)d_in[16];

    const int N = in_sizes[0] / 128;
    const int E = in_sizes[1] / 2;
    const int M = in_sizes[2] / 2;
    const int* src  = ei;
    const int* dstE = ei + E;
    const int* msrc = mei;
    const int* mdst = mei + M;

    int shift = 8;
    while ((((N - 1) >> shift) + 1) > MAXB) ++shift;
    const int nbuckets = ((N - 1) >> shift) + 1;
    long long avg = (((long long)E << shift) / N) + 1;
    int CAP = (int)((2 * avg + 2047) & ~1023LL);  // x1024 -> x32 (padding-safe)

    const size_t N64 = (size_t)N * 64;
    // bb aliases aggH..Qh ONLY (NOT Hh): Hh is written by the fused k_bfmm
    // mm1 role while bfill role still reads bb; aggH/Qh are first written by
    // the gather, which launches strictly after k_bfmm completes.
    const size_t aliasBytes = (size_t)4 * N64;   // aggH + Qh, bytes
    int nblk = NBLK_MAX;
    while (nblk > 1 && (size_t)nblk * nbuckets * CAPB * 4 > aliasBytes) --nblk;
    int pcap = (((E + nblk - 1) / nblk) + 7) & ~7;   // x8 for vectorized chunks
    nblk = (E + pcap - 1) / pcap;

    unsigned short* Hh   = (unsigned short*)d_ws;   // (N+1)*64 fp16: h1/h3/P + zero sentinel row
    unsigned short* aggH = Hh + N64 + 64;           // N*64 fp16
    unsigned short* Qh   = aggH + N64;              // N*64 fp16
    float* inv_deg = (float*)(Qh + N64);            // N
    int*   row_st  = (int*)(inv_deg + N);           // N
    int*   row_en  = row_st + N;                    // N
    int*   cnt     = row_en + N;                    // nbuckets*NBLK_MAX
    unsigned short* Wt = (unsigned short*)(cnt + (size_t)nbuckets * NBLK_MAX);  // 36928 halfs
    int*   csr     = (int*)(Wt + 36928 + 32);       // nbuckets*CAP ints
    unsigned* bb   = (unsigned*)aggH;               // nbuckets*nblk*CAPB ints (pre-gather)
    float* outf = (float*)d_out;

    const int nbN = (N + 63) / 64;
    const int nbM1 = (N + 127) / 128;               // mm1 role: 128 rows/block
    const int nbM = (int)(((long long)M * 8 + 255) / 256);
    const int nbG = (int)(((long long)N * 64 + 255) / 256);

    // ---- CSR build + weight prep (fused into k_part block 0)
    k_part<<<nblk, PART_BS, 0, stream>>>(src, dstE, bb, cnt,
                                         lin1_w, c1_wl, c1_wr, lin2_w,
                                         c2_wl, c2_wr, mlp_w1, mlp_w2, Wt,
                                         E, shift, pcap, nblk, nbuckets);

    // ---- fused: CSR bucket fill + mm1 (disjoint outputs; bb not aliased
    //      with Hh) ----
    k_bfmm<<<nbuckets + nbM1, 512, 0, stream>>>(bb, cnt, row_st, row_en,
                                                inv_deg, csr, N, shift, CAP,
                                                nblk, nbuckets,
                                                x, Wt + 0, lin1_b, Hh);

    // sage1 + lin2 fused
    k_gather_h<<<nbG, 256, 0, stream>>>((const _Float16*)Hh, csr, row_st, row_en,
                                        inv_deg, (_Float16*)aggH, N);
    k_mm23<<<nbN, 256, 0, stream>>>(aggH, Hh, Wt + 8192, c1_bl,
                                    Wt + 16384, lin2_b, Hh, N);

    // sage2 + P/Q fused
    k_gather_h<<<nbG, 256, 0, stream>>>((const _Float16*)Hh, csr, row_st, row_en,
                                        inv_deg, (_Float16*)aggH, N);
    k_mm456<<<nbN, 256, 0, stream>>>(aggH, Hh, Wt + 20480, c2_bl,
                                     Wt + 28672, Wt + 32768, mlp_b1,
                                     Hh, Qh, N);

    // edge scoring
    k_score_h<<<nbM, 256, 0, stream>>>((const _Float16*)Hh, (const _Float16*)Qh,
                                       msrc, mdst, (const _Float16*)(Wt + 36864),
                                       mlp_b2, outf, M);
}

// Round 10
// 362.571 us; speedup vs baseline: 1.0146x; 1.0146x over previous
//
#include <hip/hip_runtime.h>
#include <math.h>

#define MAXB 512
#define PART_BS 1024
#define NBLK_MAX 248
#define CAPB 96  // per-(block,bucket) segment capacity; %8==0

typedef _Float16 f16;
typedef __attribute__((ext_vector_type(2))) _Float16 f16x2;
typedef __attribute__((ext_vector_type(4))) _Float16 f16x4;
typedef __attribute__((ext_vector_type(8))) _Float16 f16x8;
typedef __attribute__((ext_vector_type(4))) float f32x4;

static __device__ __forceinline__ unsigned short f2h(float f) {
    f16 h = (f16)f; return *(unsigned short*)&h;
}

// ========== single-pass partition into per-block private segments ==========
// bb[(bucket*nblk + blk)*CAPB + r]; weight prep distributed over blocks
// (grid-stride, ~1 element/thread on blocks 0..36 -> no straggler).
__global__ __launch_bounds__(PART_BS) void k_part(
    const int* __restrict__ src, const int* __restrict__ dst,
    unsigned* __restrict__ bb, int* __restrict__ cnt,
    const float* __restrict__ lin1_w, const float* __restrict__ c1_wl,
    const float* __restrict__ c1_wr, const float* __restrict__ lin2_w,
    const float* __restrict__ c2_wl, const float* __restrict__ c2_wr,
    const float* __restrict__ mlp_w1, const float* __restrict__ mlp_w2,
    unsigned short* __restrict__ Wt,
    int E, int shift, int pcap, int nblk, int nb) {
    __shared__ int h[MAXB];
    const int blk = blockIdx.x;
    for (int i = blk * PART_BS + (int)threadIdx.x; i < 36928; i += gridDim.x * PART_BS) {
        float v;
        if (i < 8192)       { int j = i;         int n = j >> 7, k = j & 127; v = lin1_w[k * 64 + n]; }
        else if (i < 16384) { int j = i - 8192;  int n = j >> 7, k = j & 127;
                              v = (k < 64) ? c1_wl[k * 64 + n] : c1_wr[(k - 64) * 64 + n]; }
        else if (i < 20480) { int j = i - 16384; int n = j >> 6, k = j & 63;  v = lin2_w[k * 64 + n]; }
        else if (i < 28672) { int j = i - 20480; int n = j >> 7, k = j & 127;
                              v = (k < 64) ? c2_wl[k * 64 + n] : c2_wr[(k - 64) * 64 + n]; }
        else if (i < 32768) { int j = i - 28672; int n = j >> 6, k = j & 63;  v = mlp_w1[k * 64 + n]; }
        else if (i < 36864) { int j = i - 32768; int n = j >> 6, k = j & 63;  v = mlp_w1[(k + 64) * 64 + n]; }
        else                { v = mlp_w2[i - 36864]; }
        Wt[i] = f2h(v);
    }
    const int b0 = blk * pcap;
    const int e1 = min(b0 + pcap, E);
    for (int i = threadIdx.x; i < MAXB; i += PART_BS) h[i] = 0;
    __syncthreads();
    const unsigned mask = (1u << shift) - 1u;
    for (int pos = b0 + (int)threadIdx.x * 8; pos < e1; pos += PART_BS * 8) {
        if (pos + 8 <= e1) {
            int4 d0 = *(const int4*)(dst + pos), d1 = *(const int4*)(dst + pos + 4);
            int4 s0 = *(const int4*)(src + pos), s1 = *(const int4*)(src + pos + 4);
            int dd[8] = {d0.x, d0.y, d0.z, d0.w, d1.x, d1.y, d1.z, d1.w};
            int ss[8] = {s0.x, s0.y, s0.z, s0.w, s1.x, s1.y, s1.z, s1.w};
#pragma unroll
            for (int k = 0; k < 8; ++k) {
                int b = dd[k] >> shift;
                int r = atomicAdd(&h[b], 1);
                if (r < CAPB)
                    bb[((size_t)b * nblk + blk) * CAPB + r] =
                        ((unsigned)ss[k] << shift) | ((unsigned)dd[k] & mask);
            }
        } else {
            for (int k = 0; pos + k < e1; ++k) {
                int d = dst[pos + k];
                int b = d >> shift;
                int r = atomicAdd(&h[b], 1);
                if (r < CAPB)
                    bb[((size_t)b * nblk + blk) * CAPB + r] =
                        ((unsigned)src[pos + k] << shift) | ((unsigned)d & mask);
            }
        }
    }
    __syncthreads();
    for (int i = threadIdx.x; i < nb; i += PART_BS)
        cnt[(size_t)i * nblk + blk] = min(h[i], CAPB);
}

// ========== FUSED: bfill (CSR build) + mm1 (h1 = relu(x@lin1_w+b)) ==========
// blockIdx < nbB: bfill role; else mm1 role. bb never aliases Hh (fresh
// region after csr when ws permits, else aggH/Qh), so roles are race-free.
__global__ __launch_bounds__(512) void k_bfmm(
    const unsigned* __restrict__ bb, const int* __restrict__ cnt,
    int* __restrict__ row_st, int* __restrict__ row_en,
    float* __restrict__ inv_deg, int* __restrict__ csr,
    int N, int shift, int CAP, int nblk, int nbB,
    const float* __restrict__ x, const unsigned short* __restrict__ Wtg,
    const float* __restrict__ bias, unsigned short* __restrict__ outh) {
    __shared__ alignas(16) unsigned char smem[64 * 136 * 2];  // 17408 B union
    const int t = threadIdx.x;

    if (blockIdx.x < (unsigned)nbB) {
        // ---------------- bfill role (8-wide slot batching) ----------------
        int* deg  = (int*)smem;            // 512
        int* cur  = deg + 512;             // 512
        int* s    = cur + 512;             // 512
        int* scnt = s + 512;               // NBLK_MAX
        int b = blockIdx.x;
        int lo = b << shift;
        int hi = min(N, (b + 1) << shift);
        int nn = hi - lo;
        unsigned off = (unsigned)b * CAP;
        unsigned mask = (1u << shift) - 1u;
        const unsigned* seg = bb + (size_t)b * nblk * CAPB;

        for (int i = t; i < nblk; i += 512) scnt[i] = cnt[(size_t)b * nblk + i];
        deg[t] = 0;
        __syncthreads();
        const int tot8 = (nblk * CAPB) >> 3;
        for (int q8 = t; q8 < tot8; q8 += 512) {
            int i = q8 << 3;
            int si = i / CAPB;             // compile-time-const divisor
            int r = i - si * CAPB;
            int sc = scnt[si];
            if (r < sc) {
                uint4 wA = *(const uint4*)&seg[i];
                uint4 wB = *(const uint4*)&seg[i + 4];
                int nv = min(sc - r, 8);
                unsigned ww[8] = {wA.x, wA.y, wA.z, wA.w, wB.x, wB.y, wB.z, wB.w};
#pragma unroll
                for (int k = 0; k < 8; ++k)
                    if (k < nv) atomicAdd(&deg[ww[k] & mask], 1);
            }
        }
        __syncthreads();
        int d = deg[t];
        int pd = (d + 31) & ~31;
        s[t] = pd;
        __syncthreads();
        for (int o = 1; o < 512; o <<= 1) {
            int u = (t >= o) ? s[t - o] : 0;
            __syncthreads();
            s[t] += u;
            __syncthreads();
        }
        int excl = min(s[t] - pd, CAP);
        int pe = min(excl + pd, CAP);
        cur[t] = excl;
        if (t < nn) {
            row_st[lo + t] = (int)off + excl;
            row_en[lo + t] = (int)off + pe;
            inv_deg[lo + t] = d > 0 ? 1.0f / (float)d : 0.0f;
            for (int j = excl + d; j < pe; ++j) csr[off + j] = N;  // sentinel
        }
        __syncthreads();
        for (int q8 = t; q8 < tot8; q8 += 512) {
            int i = q8 << 3;
            int si = i / CAPB;
            int r = i - si * CAPB;
            int sc = scnt[si];
            if (r < sc) {
                uint4 wA = *(const uint4*)&seg[i];
                uint4 wB = *(const uint4*)&seg[i + 4];
                int nv = min(sc - r, 8);
                unsigned ww[8] = {wA.x, wA.y, wA.z, wA.w, wB.x, wB.y, wB.z, wB.w};
#pragma unroll
                for (int k = 0; k < 8; ++k)
                    if (k < nv) {
                        int dl = (int)(ww[k] & mask);
                        int pos = atomicAdd(&cur[dl], 1);
                        if (pos < CAP) csr[off + pos] = (int)(ww[k] >> shift);
                    }
            }
        }
    } else {
        // ---------------- mm1 role: 128 rows/block, 8 waves ----------------
        unsigned short* sW = (unsigned short*)smem;   // 64*136 halfs
        const int mb = blockIdx.x - nbB;
        const int row0 = mb * 128;
        const int n = N;
        if (mb == 0 && t < 8)
            ((uint4*)(outh + (size_t)n * 64))[t] = (uint4){0, 0, 0, 0};  // sentinel row
        for (int i = t; i < 64 * 16; i += 512) {
            int nn = i >> 4, c = i & 15;
            *(uint4*)&sW[(nn * 17 + c) * 8] = *(const uint4*)&Wtg[i * 8];
        }
        __syncthreads();
        const int lane = t & 63, w = t >> 6;      // w in 0..7
        const int m = lane & 15, q = lane >> 4;
        const int gr = min(row0 + 16 * w + m, n - 1);
        const float* ar = x + (size_t)gr * 128;
        f32x4 acc[4];
#pragma unroll
        for (int c = 0; c < 4; ++c) acc[c] = (f32x4){0.f, 0.f, 0.f, 0.f};
#pragma unroll
        for (int kk = 0; kk < 4; ++kk) {
            float4 a0 = *(const float4*)(ar + kk * 32 + q * 8);
            float4 a1 = *(const float4*)(ar + kk * 32 + q * 8 + 4);
            f16x8 af;
            af[0] = (f16)a0.x; af[1] = (f16)a0.y; af[2] = (f16)a0.z; af[3] = (f16)a0.w;
            af[4] = (f16)a1.x; af[5] = (f16)a1.y; af[6] = (f16)a1.z; af[7] = (f16)a1.w;
#pragma unroll
            for (int c = 0; c < 4; ++c) {
                f16x8 bf = *(const f16x8*)&sW[((16 * c + m) * 17 + (kk * 4 + q)) * 8];
                acc[c] = __builtin_amdgcn_mfma_f32_16x16x32_f16(af, bf, acc[c], 0, 0, 0);
            }
        }
#pragma unroll
        for (int c = 0; c < 4; ++c) {
            int col = 16 * c + m;
            float bv = bias[col];
#pragma unroll
            for (int i = 0; i < 4; ++i) {
                int r = row0 + 16 * w + q * 4 + i;
                if (r < n) outh[(size_t)r * 64 + col] = f2h(fmaxf(acc[c][i] + bv, 0.f));
            }
        }
    }
}

// ====== mean aggregation v6: sentinel-padded rows, 64-row chunks ======
// lane: g = lane>>3 (row slot 0..7), sub = lane&7 (channel octet)
__global__ __launch_bounds__(256) void k_gather_h(
    const _Float16* __restrict__ hh, const int* __restrict__ csr,
    const int* __restrict__ row_st, const int* __restrict__ row_en,
    const float* __restrict__ inv_deg, _Float16* __restrict__ out, int n) {
    int node = (blockIdx.x * 256 + (int)threadIdx.x) >> 6;
    if (node >= n) return;
    int lane = threadIdx.x & 63;
    int g = lane >> 3, sub = lane & 7;
    int base = row_st[node], end = row_en[node];
    float a[8] = {0.f, 0.f, 0.f, 0.f, 0.f, 0.f, 0.f, 0.f};
#if __has_builtin(__builtin_amdgcn_fdot2)
    const f16x2 one2 = {(f16)1.f, (f16)1.f};
#endif
    for (; base + 64 <= end; base += 64) {
        int4 sA = *(const int4*)&csr[base + 4 * g];
        int4 sB = *(const int4*)&csr[base + 32 + 4 * g];
        int sidx[8] = {sA.x, sA.y, sA.z, sA.w, sB.x, sB.y, sB.z, sB.w};
        f16x8 u[8];
#pragma unroll
        for (int t = 0; t < 8; ++t)
            u[t] = *(const f16x8*)(hh + (((unsigned)sidx[t] << 6) + ((unsigned)sub << 3)));
#if __has_builtin(__builtin_amdgcn_fdot2)
#pragma unroll
        for (int t = 0; t < 8; t += 2)
#pragma unroll
            for (int j = 0; j < 8; ++j) {
                f16x2 v = {u[t][j], u[t + 1][j]};
                a[j] = __builtin_amdgcn_fdot2(v, one2, a[j], false);
            }
#else
#pragma unroll
        for (int t = 0; t < 8; ++t)
#pragma unroll
            for (int j = 0; j < 8; ++j) a[j] += (float)u[t][j];
#endif
    }
    if (base < end) {  // one 32-row tail (rows padded to x32)
        int4 sA = *(const int4*)&csr[base + 4 * g];
        int sidx[4] = {sA.x, sA.y, sA.z, sA.w};
        f16x8 u[4];
#pragma unroll
        for (int t = 0; t < 4; ++t)
            u[t] = *(const f16x8*)(hh + (((unsigned)sidx[t] << 6) + ((unsigned)sub << 3)));
#if __has_builtin(__builtin_amdgcn_fdot2)
#pragma unroll
        for (int t = 0; t < 4; t += 2)
#pragma unroll
            for (int j = 0; j < 8; ++j) {
                f16x2 v = {u[t][j], u[t + 1][j]};
                a[j] = __builtin_amdgcn_fdot2(v, one2, a[j], false);
            }
#else
#pragma unroll
        for (int t = 0; t < 4; ++t)
#pragma unroll
            for (int j = 0; j < 8; ++j) a[j] += (float)u[t][j];
#endif
    }
#pragma unroll
    for (int j = 0; j < 8; ++j) {
        a[j] += __shfl_xor(a[j], 8, 64);
        a[j] += __shfl_xor(a[j], 16, 64);
        a[j] += __shfl_xor(a[j], 32, 64);
    }
    if (g == 0) {
        float idv = inv_deg[node];
        f16x8 o;
#pragma unroll
        for (int j = 0; j < 8; ++j) o[j] = (f16)(a[j] * idv);
        *(f16x8*)(out + (((unsigned)node << 6) + ((unsigned)sub << 3))) = o;
    }
}

// ---- k_mm23 (MFMA, 2-stage): h3 = relu(relu([agg|h1]@Wc+bl) @ lin2 + b2) ----
__global__ __launch_bounds__(256) void k_mm23(
    const unsigned short* __restrict__ aggH, const unsigned short* __restrict__ h1,
    const unsigned short* __restrict__ Wcg, const float* __restrict__ bl,
    const unsigned short* __restrict__ Wl2g, const float* __restrict__ b2,
    unsigned short* __restrict__ outh, int n) {
    __shared__ alignas(16) unsigned short sm[64 * 72 + 64 * 136];
    unsigned short* hA = sm;
    unsigned short* sW = sm + 64 * 72;
    const int tid = threadIdx.x;
    const int row0 = blockIdx.x * 64;
    for (int i = tid; i < 64 * 16; i += 256) {
        int nn = i >> 4, c = i & 15;
        *(uint4*)&sW[(nn * 17 + c) * 8] = *(const uint4*)&Wcg[i * 8];
    }
    __syncthreads();
    const int lane = tid & 63, w = tid >> 6;
    const int m = lane & 15, q = lane >> 4;
    const int gr = min(row0 + 16 * w + m, n - 1);
    f32x4 acc[4];
#pragma unroll
    for (int c = 0; c < 4; ++c) acc[c] = (f32x4){0.f, 0.f, 0.f, 0.f};
#pragma unroll
    for (int kk = 0; kk < 4; ++kk) {
        const unsigned short* ap = (kk < 2)
            ? (aggH + (size_t)gr * 64 + kk * 32 + q * 8)
            : (h1 + (size_t)gr * 64 + (kk - 2) * 32 + q * 8);
        f16x8 af = *(const f16x8*)ap;
#pragma unroll
        for (int c = 0; c < 4; ++c) {
            f16x8 bf = *(const f16x8*)&sW[((16 * c + m) * 17 + (kk * 4 + q)) * 8];
            acc[c] = __builtin_amdgcn_mfma_f32_16x16x32_f16(af, bf, acc[c], 0, 0, 0);
        }
    }
#pragma unroll
    for (int c = 0; c < 4; ++c) {
        int col = 16 * c + m;
        float bv = bl[col];
#pragma unroll
        for (int i = 0; i < 4; ++i)
            hA[(16 * w + q * 4 + i) * 72 + col] = f2h(fmaxf(acc[c][i] + bv, 0.f));
    }
    __syncthreads();
    for (int i = tid; i < 64 * 8; i += 256) {
        int nn = i >> 3, c = i & 7;
        *(uint4*)&sW[(nn * 9 + c) * 8] = *(const uint4*)&Wl2g[i * 8];
    }
    __syncthreads();
    f32x4 acc2[4];
#pragma unroll
    for (int c = 0; c < 4; ++c) acc2[c] = (f32x4){0.f, 0.f, 0.f, 0.f};
#pragma unroll
    for (int kk = 0; kk < 2; ++kk) {
        f16x8 af = *(const f16x8*)&hA[(16 * w + m) * 72 + kk * 32 + q * 8];
#pragma unroll
        for (int c = 0; c < 4; ++c) {
            f16x8 bf = *(const f16x8*)&sW[((16 * c + m) * 9 + (kk * 4 + q)) * 8];
            acc2[c] = __builtin_amdgcn_mfma_f32_16x16x32_f16(af, bf, acc2[c], 0, 0, 0);
        }
    }
#pragma unroll
    for (int c = 0; c < 4; ++c) {
        int col = 16 * c + m;
        float bv = b2[col];
#pragma unroll
        for (int i = 0; i < 4; ++i) {
            int r = row0 + 16 * w + q * 4 + i;
            if (r < n) outh[(size_t)r * 64 + col] = f2h(fmaxf(acc2[c][i] + bv, 0.f));
        }
    }
}

// ---- k_mm456 (MFMA, 2-stage): h4=relu([agg2|h3]@Wc2+bl); P=h4@Wp+b1; Q=h4@Wq
__global__ __launch_bounds__(256) void k_mm456(
    const unsigned short* __restrict__ aggH, const unsigned short* __restrict__ h3,
    const unsigned short* __restrict__ Wcg, const float* __restrict__ bl,
    const unsigned short* __restrict__ Wpg, const unsigned short* __restrict__ Wqg,
    const float* __restrict__ b1, unsigned short* __restrict__ Ph,
    unsigned short* __restrict__ Qh, int n) {
    __shared__ alignas(16) unsigned short sm[64 * 72 + 2 * 64 * 72];
    unsigned short* hA = sm;
    unsigned short* sW = sm + 64 * 72;
    const int tid = threadIdx.x;
    const int row0 = blockIdx.x * 64;
    for (int i = tid; i < 64 * 16; i += 256) {
        int nn = i >> 4, c = i & 15;
        *(uint4*)&sW[(nn * 17 + c) * 8] = *(const uint4*)&Wcg[i * 8];
    }
    __syncthreads();
    const int lane = tid & 63, w = tid >> 6;
    const int m = lane & 15, q = lane >> 4;
    const int gr = min(row0 + 16 * w + m, n - 1);
    f32x4 acc[4];
#pragma unroll
    for (int c = 0; c < 4; ++c) acc[c] = (f32x4){0.f, 0.f, 0.f, 0.f};
#pragma unroll
    for (int kk = 0; kk < 4; ++kk) {
        const unsigned short* ap = (kk < 2)
            ? (aggH + (size_t)gr * 64 + kk * 32 + q * 8)
            : (h3 + (size_t)gr * 64 + (kk - 2) * 32 + q * 8);
        f16x8 af = *(const f16x8*)ap;
#pragma unroll
        for (int c = 0; c < 4; ++c) {
            f16x8 bf = *(const f16x8*)&sW[((16 * c + m) * 17 + (kk * 4 + q)) * 8];
            acc[c] = __builtin_amdgcn_mfma_f32_16x16x32_f16(af, bf, acc[c], 0, 0, 0);
        }
    }
#pragma unroll
    for (int c = 0; c < 4; ++c) {
        int col = 16 * c + m;
        float bv = bl[col];
#pragma unroll
        for (int i = 0; i < 4; ++i)
            hA[(16 * w + q * 4 + i) * 72 + col] = f2h(fmaxf(acc[c][i] + bv, 0.f));
    }
    __syncthreads();
    for (int i = tid; i < 64 * 8; i += 256) {
        int nn = i >> 3, c = i & 7;
        *(uint4*)&sW[(nn * 9 + c) * 8] = *(const uint4*)&Wpg[i * 8];
        *(uint4*)&sW[4608 + (nn * 9 + c) * 8] = *(const uint4*)&Wqg[i * 8];
    }
    __syncthreads();
    f32x4 accP[4], accQ[4];
#pragma unroll
    for (int c = 0; c < 4; ++c) {
        accP[c] = (f32x4){0.f, 0.f, 0.f, 0.f};
        accQ[c] = (f32x4){0.f, 0.f, 0.f, 0.f};
    }
#pragma unroll
    for (int kk = 0; kk < 2; ++kk) {
        f16x8 af = *(const f16x8*)&hA[(16 * w + m) * 72 + kk * 32 + q * 8];
#pragma unroll
        for (int c = 0; c < 4; ++c) {
            f16x8 bp = *(const f16x8*)&sW[((16 * c + m) * 9 + (kk * 4 + q)) * 8];
            f16x8 bq = *(const f16x8*)&sW[4608 + ((16 * c + m) * 9 + (kk * 4 + q)) * 8];
            accP[c] = __builtin_amdgcn_mfma_f32_16x16x32_f16(af, bp, accP[c], 0, 0, 0);
            accQ[c] = __builtin_amdgcn_mfma_f32_16x16x32_f16(af, bq, accQ[c], 0, 0, 0);
        }
    }
#pragma unroll
    for (int c = 0; c < 4; ++c) {
        int col = 16 * c + m;
        float bv = b1[col];
#pragma unroll
        for (int i = 0; i < 4; ++i) {
            int r = row0 + 16 * w + q * 4 + i;
            if (r < n) {
                Ph[(size_t)r * 64 + col] = f2h(accP[c][i] + bv);
                Qh[(size_t)r * 64 + col] = f2h(accQ[c][i]);
            }
        }
    }
}

// ---- edge scorer v3: 8 lanes/edge, f16x8, 16 loads in flight per wave ----
__global__ __launch_bounds__(256) void k_score_h(
    const _Float16* __restrict__ P, const _Float16* __restrict__ Q,
    const int* __restrict__ msrc, const int* __restrict__ mdst,
    const _Float16* __restrict__ w2h, const float* __restrict__ b2,
    float* __restrict__ out, int M) {
    int gid = blockIdx.x * 256 + threadIdx.x;
    int e = gid >> 3;
    if (e >= M) return;
    int l = gid & 7;
    int s = msrc[e], d = mdst[e];
    f16x8 p = *(const f16x8*)(P + (((unsigned)s << 6) + ((unsigned)l << 3)));
    f16x8 q = *(const f16x8*)(Q + (((unsigned)d << 6) + ((unsigned)l << 3)));
    f16x8 w = *(const f16x8*)(w2h + ((unsigned)l << 3));
    f16x8 u = p + q;
    f16x8 z = {(f16)0, (f16)0, (f16)0, (f16)0, (f16)0, (f16)0, (f16)0, (f16)0};
    u = __builtin_elementwise_max(u, z);
    float partial;
#if __has_builtin(__builtin_amdgcn_fdot2)
    f16x2 u01 = {u[0], u[1]}, u23 = {u[2], u[3]}, u45 = {u[4], u[5]}, u67 = {u[6], u[7]};
    f16x2 w01 = {w[0], w[1]}, w23 = {w[2], w[3]}, w45 = {w[4], w[5]}, w67 = {w[6], w[7]};
    partial = __builtin_amdgcn_fdot2(u01, w01,
              __builtin_amdgcn_fdot2(u23, w23,
              __builtin_amdgcn_fdot2(u45, w45,
              __builtin_amdgcn_fdot2(u67, w67, 0.f, false), false), false), false);
#else
    partial = 0.f;
#pragma unroll
    for (int i = 0; i < 8; ++i) partial += (float)u[i] * (float)w[i];
#endif
    partial += __shfl_xor(partial, 1, 8);
    partial += __shfl_xor(partial, 2, 8);
    partial += __shfl_xor(partial, 4, 8);
    if (l == 0) {
        float xx = partial + b2[0];
        float t = __expf(2.f * xx);
        out[e] = (t - 1.f) / (t + 1.f);
    }
}

extern "C" void kernel_launch(void* const* d_in, const int* in_sizes, int n_in,
                              void* d_out, int out_size, void* d_ws, size_t ws_size,
                              hipStream_t stream) {
    const float* x      = (const float*)d_in[0];
    const int*   ei     = (const int*)d_in[1];
    const int*   mei    = (const int*)d_in[2];
    const float* lin1_w = (const float*)d_in[3];
    const float* lin1_b = (const float*)d_in[4];
    const float* lin2_w = (const float*)d_in[5];
    const float* lin2_b = (const float*)d_in[6];
    const float* c1_wl  = (const float*)d_in[7];
    const float* c1_bl  = (const float*)d_in[8];
    const float* c1_wr  = (const float*)d_in[9];
    const float* c2_wl  = (const float*)d_in[10];
    const float* c2_bl  = (const float*)d_in[11];
    const float* c2_wr  = (const float*)d_in[12];
    const float* mlp_w1 = (const float*)d_in[13];
    const float* mlp_b1 = (const float*)d_in[14];
    const float* mlp_w2 = (const float*)d_in[15];
    const float* mlp_b2 = (const float*)d_in[16];

    const int N = in_sizes[0] / 128;
    const int E = in_sizes[1] / 2;
    const int M = in_sizes[2] / 2;
    const int* src  = ei;
    const int* dstE = ei + E;
    const int* msrc = mei;
    const int* mdst = mei + M;

    int shift = 8;
    while ((((N - 1) >> shift) + 1) > MAXB) ++shift;
    const int nbuckets = ((N - 1) >> shift) + 1;
    long long avg = (((long long)E << shift) / N) + 1;
    int CAP = (int)((2 * avg + 2047) & ~1023LL);  // x1024 -> x32 (padding-safe)

    const size_t N64 = (size_t)N * 64;
    unsigned short* Hh   = (unsigned short*)d_ws;   // (N+1)*64 fp16: h1/h3/P + zero sentinel row
    unsigned short* aggH = Hh + N64 + 64;           // N*64 fp16
    unsigned short* Qh   = aggH + N64;              // N*64 fp16
    float* inv_deg = (float*)(Qh + N64);            // N
    int*   row_st  = (int*)(inv_deg + N);           // N
    int*   row_en  = row_st + N;                    // N
    int*   cnt     = row_en + N;                    // nbuckets*NBLK_MAX
    unsigned short* Wt = (unsigned short*)(cnt + (size_t)nbuckets * NBLK_MAX);  // 36928 halfs
    int*   csr     = (int*)(Wt + 36928 + 32);       // nbuckets*CAP ints
    float* outf = (float*)d_out;

    // bb placement: PREFER a fresh region after csr (no aliasing, nblk=248,
    // full k_part occupancy). Fall back to aliasing aggH..Qh (bb consumed
    // before the first gather writes aggH) with reduced nblk if ws is tight.
    unsigned* bb_fresh = (unsigned*)(csr + (size_t)nbuckets * CAP);
    size_t used = (size_t)((char*)bb_fresh - (char*)d_ws);
    size_t need = (size_t)NBLK_MAX * nbuckets * CAPB * 4;
    unsigned* bb;
    int nblk;
    if (ws_size >= used + need) {
        bb = bb_fresh;
        nblk = NBLK_MAX;
    } else {
        bb = (unsigned*)aggH;
        const size_t aliasBytes = (size_t)4 * N64;   // aggH + Qh, bytes
        nblk = NBLK_MAX;
        while (nblk > 1 && (size_t)nblk * nbuckets * CAPB * 4 > aliasBytes) --nblk;
    }
    int pcap = (((E + nblk - 1) / nblk) + 7) & ~7;   // x8 for vectorized chunks
    nblk = (E + pcap - 1) / pcap;

    const int nbN = (N + 63) / 64;
    const int nbM1 = (N + 127) / 128;               // mm1 role: 128 rows/block
    const int nbM = (int)(((long long)M * 8 + 255) / 256);
    const int nbG = (int)(((long long)N * 64 + 255) / 256);

    // ---- CSR build + weight prep (prep distributed across k_part blocks)
    k_part<<<nblk, PART_BS, 0, stream>>>(src, dstE, bb, cnt,
                                         lin1_w, c1_wl, c1_wr, lin2_w,
                                         c2_wl, c2_wr, mlp_w1, mlp_w2, Wt,
                                         E, shift, pcap, nblk, nbuckets);

    // ---- fused: CSR bucket fill + mm1 (disjoint outputs; bb never aliases
    //      Hh) ----
    k_bfmm<<<nbuckets + nbM1, 512, 0, stream>>>(bb, cnt, row_st, row_en,
                                                inv_deg, csr, N, shift, CAP,
                                                nblk, nbuckets,
                                                x, Wt + 0, lin1_b, Hh);

    // sage1 + lin2 fused
    k_gather_h<<<nbG, 256, 0, stream>>>((const _Float16*)Hh, csr, row_st, row_en,
                                        inv_deg, (_Float16*)aggH, N);
    k_mm23<<<nbN, 256, 0, stream>>>(aggH, Hh, Wt + 8192, c1_bl,
                                    Wt + 16384, lin2_b, Hh, N);

    // sage2 + P/Q fused
    k_gather_h<<<nbG, 256, 0, stream>>>((const _Float16*)Hh, csr, row_st, row_en,
                                        inv_deg, (_Float16*)aggH, N);
    k_mm456<<<nbN, 256, 0, stream>>>(aggH, Hh, Wt + 20480, c2_bl,
                                     Wt + 28672, Wt + 32768, mlp_b1,
                                     Hh, Qh, N);

    // edge scoring
    k_score_h<<<nbM, 256, 0, stream>>>((const _Float16*)Hh, (const _Float16*)Qh,
                                       msrc, mdst, (const _Float16*)(Wt + 36864),
                                       mlp_b2, outf, M);
}